// Round 1
// baseline (917.053 us; speedup 1.0000x reference)
//
#include <hip/hip_runtime.h>
#include <math.h>

#define Dd   512
#define Hh   8
#define Tt   4
#define HDd  64
#define Bb   16
#define Nn   8192
#define HTc  32
#define KS   64
#define NTOK (Bb*Nn)
#define PRUNEc 0.001f
#define EPSc   1e-8f

// ---- workspace byte offsets (total ~18.9 MiB) ----
#define WS_G2     0u        // 32*512 f  (g-scaled folded K-proj)
#define WS_C1     65536u    // 32 f
#define WS_C0     65664u    // 32 f
#define WS_M      65792u    // 512 f  softmax row max
#define WS_L      67840u    // 512 f  softmax row sum
#define WS_TOPW   69888u    // 64*64 f
#define WS_TOPI   86272u    // 64*64 int
#define WS_FLAG   102656u   // int (mask dtype flag)
#define WS_MEAN   131072u   // 131072 f per-token LN mean
#define WS_INV    655360u   // 131072 f per-token LN rsqrt
#define WS_MASK8  1179648u  // 131072 bytes expanded mask
#define WS_SCORES 2097152u  // 16 MiB scores[b][h][t][n]

// ---------- mask dtype detection (bool may arrive as i32 / u8 / f32) ----------
__global__ void tap_detect(const unsigned* mraw, int* flag){
  int tid = threadIdx.x;
  if (tid == 0) *flag = 0;
  __syncthreads();
  int f = 0;
  for (int i = tid; i < NTOK/4; i += 256){   // read only first NTOK bytes (safe for all layouts)
    unsigned v = mraw[i];
    if (v == 0x3f800000u) f |= 2;            // float32 1.0 pattern -> float layout
    else if (v & ~1u)     f |= 1;            // packed bytes
  }
  if (f) atomicOr(flag, f);
}

__global__ void tap_mask(const void* mraw, const int* flag, unsigned char* m8){
  int i = blockIdx.x*256 + threadIdx.x;
  int fl = *flag;
  unsigned char m;
  if (fl & 2)      m = (((const float*)mraw)[i] != 0.0f);
  else if (fl & 1) m = (((const unsigned char*)mraw)[i] != 0);
  else             m = (((const int*)mraw)[i] != 0);
  m8[i] = m;
}

// ---------- fold query path: G2[ht][j], C1[ht], C0[ht] ----------
// score[n][ht] = inv_n*(x_n . G2[ht] - mean_n*C1[ht]) + C0[ht]
__global__ void tap_prep(const float* q, const float* ipw, const float* ipb,
                         const float* pre_g, const float* pre_b,
                         const float* q_g, const float* q_b, const float* log_tau,
                         float* G2, float* C1, float* C0){
  __shared__ float query[Tt][Dd];
  __shared__ float qps[HDd];
  __shared__ float red[256];
  int tid = threadIdx.x;
  int ht = blockIdx.x;           // = h*T + t
  int h = ht >> 2, t = ht & 3;
  float tau = expf(log_tau[0]);
  tau = fminf(fmaxf(tau, 0.1f), 10.0f);
  float itau = 1.0f / tau;
  int wv = tid >> 6, lane = tid & 63;
  { // LN of q rows (wave per row), all 4 rows redundantly per block
    const float* qr = q + wv*Dd;
    float s = 0.f, ss = 0.f;
    for (int j = lane; j < Dd; j += 64){ float x = qr[j]; s += x; ss += x*x; }
    #pragma unroll
    for (int off = 32; off; off >>= 1){ s += __shfl_down(s, off); ss += __shfl_down(ss, off); }
    s = __shfl(s, 0); ss = __shfl(ss, 0);
    float mean = s * (1.f/Dd);
    float var  = ss * (1.f/Dd) - mean*mean;
    float inv  = rsqrtf(var + 1e-5f);
    for (int j = lane; j < Dd; j += 64){
      float x = qr[j];
      query[wv][j] = ((x - mean)*inv*q_g[j] + q_b[j]) * itau;
    }
  }
  __syncthreads();
  { // qp[d] = query[t] . wq[h*64+d] + bq   (4 threads per output)
    int d = tid >> 2, sub = tid & 3;
    int i = h*HDd + d;
    const float* wrow = ipw + (size_t)i*Dd;
    float acc = 0.f;
    int j0 = sub*128;
    for (int j = 0; j < 128; ++j) acc += query[t][j0+j]*wrow[j0+j];
    red[tid] = acc;
    __syncthreads();
    if (sub == 0) qps[d] = red[tid]+red[tid+1]+red[tid+2]+red[tid+3] + ipb[i];
    __syncthreads();
  }
  float c1p = 0.f, c0p = 0.f;
  for (int jj = 0; jj < 2; ++jj){
    int j = tid + jj*256;
    float acc = 0.f;
    #pragma unroll 8
    for (int d = 0; d < HDd; ++d)
      acc += qps[d] * ipw[(size_t)(Dd + h*HDd + d)*Dd + j];
    float w2 = acc * 0.125f;          // 1/sqrt(HD)
    float g2 = w2 * pre_g[j];
    G2[ht*Dd + j] = g2;
    c1p += g2;
    c0p += w2 * pre_b[j];
  }
  if (tid < HDd) c0p += qps[tid] * ipb[Dd + h*HDd + tid] * 0.125f;  // bk term
  red[tid] = c1p; __syncthreads();
  for (int s = 128; s; s >>= 1){ if (tid < s) red[tid] += red[tid+s]; __syncthreads(); }
  if (tid == 0) C1[ht] = red[0];
  __syncthreads();
  red[tid] = c0p; __syncthreads();
  for (int s = 128; s; s >>= 1){ if (tid < s) red[tid] += red[tid+s]; __syncthreads(); }
  if (tid == 0) C0[ht] = red[0];
}

// ---------- main: fused LN-stats + 32-way GEMV over all tokens ----------
__global__ __launch_bounds__(256, 4) void tap_scores(const float* tokens, const float* G2,
    const float* C1, const float* C0, float* scores, float* meanw, float* invw){
  __shared__ float4 xt[16][129];              // 16 tokens x 512f, padded stride
  __shared__ float smean[16], sinv[16];
  int tid = threadIdx.x;
  size_t t0 = (size_t)blockIdx.x * 16;
  const float4* tok4 = ((const float4*)tokens) + t0*128;
  #pragma unroll
  for (int i = 0; i < 8; ++i){
    int f = tid + i*256;
    xt[f >> 7][f & 127] = tok4[f];
  }
  __syncthreads();
  { // LN stats: 16 threads per row
    int r = tid >> 4, l16 = tid & 15;
    float s = 0.f, ss = 0.f;
    #pragma unroll
    for (int c = 0; c < 8; ++c){
      float4 v = xt[r][l16*8 + c];
      s  += v.x+v.y+v.z+v.w;
      ss += v.x*v.x+v.y*v.y+v.z*v.z+v.w*v.w;
    }
    #pragma unroll
    for (int off = 8; off; off >>= 1){ s += __shfl_down(s, off, 16); ss += __shfl_down(ss, off, 16); }
    if (l16 == 0){
      float mean = s*(1.f/512.f);
      float var  = ss*(1.f/512.f) - mean*mean;
      float inv  = rsqrtf(var + 1e-5f);
      smean[r] = mean; sinv[r] = inv;
      meanw[t0 + r] = mean; invw[t0 + r] = inv;
    }
  }
  __syncthreads();
  // wave handles 4 ht-pairs x 16 tokens; G2 loads are wave-16-broadcast (L1-friendly)
  int wv = tid >> 6, lane = tid & 63;
  int rr = lane & 15, hq = lane >> 4;
  int ht0 = wv*4 + hq, ht1 = ht0 + 16;
  const float4* g0 = (const float4*)(G2 + ht0*Dd);
  const float4* g1 = (const float4*)(G2 + ht1*Dd);
  float a0 = 0.f, a1 = 0.f;
  #pragma unroll 4
  for (int j4 = 0; j4 < 128; ++j4){
    float4 x = xt[rr][j4];
    float4 p = g0[j4];
    float4 r4 = g1[j4];
    a0 += x.x*p.x + x.y*p.y + x.z*p.z + x.w*p.w;
    a1 += x.x*r4.x + x.y*r4.y + x.z*r4.z + x.w*r4.w;
  }
  float mean = smean[rr], inv = sinv[rr];
  float s0 = inv*(a0 - mean*C1[ht0]) + C0[ht0];
  float s1 = inv*(a1 - mean*C1[ht1]) + C0[ht1];
  size_t tok = t0 + rr;
  int b = (int)(tok >> 13);
  int n = (int)(tok & 8191);
  scores[((size_t)(b*HTc + ht0))*Nn + n] = s0;
  scores[((size_t)(b*HTc + ht1))*Nn + n] = s1;
}

// ---------- per-(b,h,t) masked softmax normalizers ----------
__global__ void tap_norm(const float* scores, const unsigned char* m8, float* mrow, float* lrow){
  int R = blockIdx.x;                  // b*32 + ht
  int b = R >> 5;
  const float* srow = scores + (size_t)R*Nn;
  const unsigned char* mk = m8 + b*Nn;
  int tid = threadIdx.x;
  int wv = tid >> 6, lane = tid & 63;
  __shared__ float r4[4];
  float v[32];
  float mx = -1e30f;
  #pragma unroll
  for (int i = 0; i < 32; ++i){
    int n = tid + i*256;
    float s = srow[n];
    v[i] = mk[n] ? -1e30f : s;
    mx = fmaxf(mx, v[i]);
  }
  #pragma unroll
  for (int off = 32; off; off >>= 1) mx = fmaxf(mx, __shfl_down(mx, off));
  if (lane == 0) r4[wv] = mx;
  __syncthreads();
  mx = fmaxf(fmaxf(r4[0], r4[1]), fmaxf(r4[2], r4[3]));
  float se = 0.f;
  #pragma unroll
  for (int i = 0; i < 32; ++i) se += expf(v[i] - mx);
  #pragma unroll
  for (int off = 32; off; off >>= 1) se += __shfl_down(se, off);
  __syncthreads();
  if (lane == 0) r4[wv] = se;
  __syncthreads();
  if (tid == 0){ mrow[R] = mx; lrow[R] = r4[0]+r4[1]+r4[2]+r4[3]; }
}

// ---------- per-(b,t): alpha, prune, fallback, exact top-64 ----------
__global__ void tap_alpha(const float* scores, const unsigned char* m8,
                          const float* mrow, const float* lrow,
                          float* topw, int* topi){
  __shared__ float av[Nn];
  __shared__ float rv[4]; __shared__ int ri[4];
  __shared__ int sI;
  int bt = blockIdx.x;
  int b = bt >> 2, t = bt & 3;
  int tid = threadIdx.x;
  int wv = tid >> 6, lane = tid & 63;
  const unsigned char* mk = m8 + b*Nn;
  float mh[Hh], il[Hh];
  const float* srows[Hh];
  #pragma unroll
  for (int h = 0; h < Hh; ++h){
    int R = b*HTc + h*Tt + t;
    mh[h] = mrow[R];
    il[h] = 1.0f / lrow[R];
    srows[h] = scores + (size_t)R*Nn;
  }
  float lsum = 0.f;
  float bvv = -2.f; int bii = 1<<30;
  for (int i = 0; i < 32; ++i){
    int n = tid + i*256;
    float a = 0.f;
    if (!mk[n]){
      #pragma unroll
      for (int h = 0; h < Hh; ++h) a += expf(srows[h][n] - mh[h]) * il[h];
      a *= 0.125f;   // mean over heads
    }
    av[n] = a;
    lsum += a;
    float bb = mk[n] ? -1.f : a;
    if (bb > bvv || (bb == bvv && n < bii)){ bvv = bb; bii = n; }
  }
  #pragma unroll
  for (int off = 32; off; off >>= 1) lsum += __shfl_down(lsum, off);
  if (lane == 0) rv[wv] = lsum;
  __syncthreads();
  float Sall = rv[0]+rv[1]+rv[2]+rv[3];
  // argmax for fallback (value desc, index asc)
  #pragma unroll
  for (int off = 32; off; off >>= 1){
    float ov = __shfl_down(bvv, off);
    int   oi = __shfl_down(bii, off);
    if (ov > bvv || (ov == bvv && oi < bii)){ bvv = ov; bii = oi; }
  }
  __syncthreads();
  if (lane == 0){ rv[wv] = bvv; ri[wv] = bii; }
  __syncthreads();
  if (tid == 0){
    float bv2 = rv[0]; int bi2 = ri[0];
    for (int w2 = 1; w2 < 4; ++w2)
      if (rv[w2] > bv2 || (rv[w2] == bv2 && ri[w2] < bi2)){ bv2 = rv[w2]; bi2 = ri[w2]; }
    sI = bi2;
  }
  __syncthreads();
  int argmax0 = sI;
  float f1 = 1.0f / fmaxf(Sall, EPSc);
  float s2l = 0.f;
  for (int i = 0; i < 32; ++i){
    int n = tid + i*256;
    float x = av[n]*f1;
    x = (x < PRUNEc) ? 0.f : x;
    av[n] = x;
    s2l += x;
  }
  #pragma unroll
  for (int off = 32; off; off >>= 1) s2l += __shfl_down(s2l, off);
  __syncthreads();
  if (lane == 0) rv[wv] = s2l;
  __syncthreads();
  float S2 = rv[0]+rv[1]+rv[2]+rv[3];
  if (S2 <= EPSc){                      // uniform branch
    for (int i = 0; i < 32; ++i) av[tid + i*256] = 0.f;
    __syncthreads();
    if (tid == 0) av[argmax0] = 1.0f;
    S2 = 1.0f;
  }
  __syncthreads();
  float f2 = 1.0f / fmaxf(S2, EPSc);
  // iterative top-64 extraction, exact jax tie-break
  for (int k = 0; k < KS; ++k){
    float bv = -1.f; int bi = 1<<30;
    for (int i = 0; i < 32; ++i){
      int n = tid + i*256;
      float x = av[n];
      if (x > bv || (x == bv && n < bi)){ bv = x; bi = n; }
    }
    #pragma unroll
    for (int off = 32; off; off >>= 1){
      float ov = __shfl_down(bv, off);
      int   oi = __shfl_down(bi, off);
      if (ov > bv || (ov == bv && oi < bi)){ bv = ov; bi = oi; }
    }
    if (lane == 0){ rv[wv] = bv; ri[wv] = bi; }
    __syncthreads();
    if (tid == 0){
      float bb = rv[0]; int bj = ri[0];
      for (int w2 = 1; w2 < 4; ++w2)
        if (rv[w2] > bb || (rv[w2] == bb && ri[w2] < bj)){ bb = rv[w2]; bj = ri[w2]; }
      topw[bt*KS + k] = bb * f2;
      topi[bt*KS + k] = bj;
      av[bj] = -1.f;                    // consume
    }
    __syncthreads();
  }
}

// ---------- pooling: u = sum_k w_k*normed_k (LN folded via saved stats), then u@wv^T ----------
__global__ void tap_pool(const float* tokens, const float* ipw, const float* ipb,
                         const float* pre_g, const float* pre_b,
                         const float* meanw, const float* invw,
                         const float* topw, const int* topi, float* out){
  __shared__ float wk_[KS]; __shared__ int rk_[KS];
  __shared__ float coeff[KS];
  __shared__ __align__(16) float u[Dd];
  __shared__ float sW, sS;
  int bt = blockIdx.x;
  int b = bt >> 2;
  int tid = threadIdx.x;
  if (tid < KS){ wk_[tid] = topw[bt*KS + tid]; rk_[tid] = topi[bt*KS + tid]; }
  __syncthreads();
  if (tid < KS){
    float v = wk_[tid];
    #pragma unroll
    for (int off = 32; off; off >>= 1) v += __shfl_down(v, off);
    if (tid == 0) sW = v;
  }
  __syncthreads();
  float sumw = sW;
  float Winv = 1.0f / fmaxf(sumw, EPSc);
  float Wn   = sumw * Winv;
  if (tid < KS){
    int n = rk_[tid];
    float mk = meanw[(size_t)b*Nn + n];
    float ik = invw [(size_t)b*Nn + n];
    float wn = wk_[tid] * Winv;
    coeff[tid] = wn * ik;
    float sp = wn * mk * ik;
    #pragma unroll
    for (int off = 32; off; off >>= 1) sp += __shfl_down(sp, off);
    if (tid == 0) sS = sp;
  }
  __syncthreads();
  float Sv = sS;
  int d0 = tid, d1 = tid + 256;
  float acc0 = 0.f, acc1 = 0.f;
  for (int k = 0; k < KS; ++k){
    float c = coeff[k];
    if (c != 0.f){
      const float* xr = tokens + ((size_t)b*Nn + rk_[k])*Dd;
      acc0 = fmaf(c, xr[d0], acc0);
      acc1 = fmaf(c, xr[d1], acc1);
    }
  }
  u[d0] = pre_g[d0]*(acc0 - Sv) + pre_b[d0]*Wn;
  u[d1] = pre_g[d1]*(acc1 - Sv) + pre_b[d1]*Wn;
  __syncthreads();
  const float4* u4 = (const float4*)u;
  const float4* w0 = (const float4*)(ipw + (size_t)(2*Dd + d0)*Dd);
  const float4* w1 = (const float4*)(ipw + (size_t)(2*Dd + d1)*Dd);
  float o0 = 0.f, o1 = 0.f;
  #pragma unroll 4
  for (int j4 = 0; j4 < 128; ++j4){
    float4 uu = u4[j4];
    float4 a = w0[j4], c = w1[j4];
    o0 += uu.x*a.x + uu.y*a.y + uu.z*a.z + uu.w*a.w;
    o1 += uu.x*c.x + uu.y*c.y + uu.z*c.z + uu.w*c.w;
  }
  out[bt*Dd + d0] = o0 + Wn*ipb[2*Dd + d0];
  out[bt*Dd + d1] = o1 + Wn*ipb[2*Dd + d1];
}

extern "C" void kernel_launch(void* const* d_in, const int* in_sizes, int n_in,
                              void* d_out, int out_size, void* d_ws, size_t ws_size,
                              hipStream_t stream){
  const float* tokens = (const float*)d_in[0];
  const void*  kpm    = d_in[1];
  const float* q      = (const float*)d_in[2];
  const float* ipw    = (const float*)d_in[3];
  const float* ipb    = (const float*)d_in[4];
  const float* pre_g  = (const float*)d_in[5];
  const float* pre_b  = (const float*)d_in[6];
  const float* q_g    = (const float*)d_in[7];
  const float* q_b    = (const float*)d_in[8];
  const float* ltau   = (const float*)d_in[9];
  char* ws = (char*)d_ws;
  float* G2    = (float*)(ws + WS_G2);
  float* C1    = (float*)(ws + WS_C1);
  float* C0    = (float*)(ws + WS_C0);
  float* mrow  = (float*)(ws + WS_M);
  float* lrow  = (float*)(ws + WS_L);
  float* topwv = (float*)(ws + WS_TOPW);
  int*   topiv = (int*)  (ws + WS_TOPI);
  int*   flag  = (int*)  (ws + WS_FLAG);
  float* meanw = (float*)(ws + WS_MEAN);
  float* invw  = (float*)(ws + WS_INV);
  unsigned char* m8 = (unsigned char*)(ws + WS_MASK8);
  float* scores = (float*)(ws + WS_SCORES);
  float* out = (float*)d_out;

  hipLaunchKernelGGL(tap_detect, dim3(1), dim3(256), 0, stream, (const unsigned*)kpm, flag);
  hipLaunchKernelGGL(tap_mask,   dim3(NTOK/256), dim3(256), 0, stream, kpm, flag, m8);
  hipLaunchKernelGGL(tap_prep,   dim3(HTc), dim3(256), 0, stream,
                     q, ipw, ipb, pre_g, pre_b, q_g, q_b, ltau, G2, C1, C0);
  hipLaunchKernelGGL(tap_scores, dim3(NTOK/16), dim3(256), 0, stream,
                     tokens, G2, C1, C0, scores, meanw, invw);
  hipLaunchKernelGGL(tap_norm,   dim3(Bb*HTc), dim3(256), 0, stream, scores, m8, mrow, lrow);
  hipLaunchKernelGGL(tap_alpha,  dim3(Bb*Tt), dim3(256), 0, stream,
                     scores, m8, mrow, lrow, topwv, topiv);
  hipLaunchKernelGGL(tap_pool,   dim3(Bb*Tt), dim3(256), 0, stream,
                     tokens, ipw, ipb, pre_g, pre_b, meanw, invw, topwv, topiv, out);
}

// Round 2
// 618.644 us; speedup vs baseline: 1.4824x; 1.4824x over previous
//
#include <hip/hip_runtime.h>
#include <math.h>

#define Dd   512
#define Hh   8
#define Tt   4
#define HDd  64
#define Bb   16
#define Nn   8192
#define HTc  32
#define KS   64
#define NTOK (Bb*Nn)
#define PRUNEc 0.001f
#define EPSc   1e-8f

// ---- workspace byte offsets (total ~18.9 MiB) ----
#define WS_G2     0u        // 32*512 f  (g-scaled folded K-proj)
#define WS_C1     65536u    // 32 f
#define WS_C0     65664u    // 32 f
#define WS_M      65792u    // 512 f  softmax row max
#define WS_L      67840u    // 512 f  softmax row sum
#define WS_TOPW   69888u    // 64*64 f
#define WS_TOPI   86272u    // 64*64 int
#define WS_FLAG   102656u   // int (mask dtype flag)
#define WS_MEAN   131072u   // 131072 f per-token LN mean
#define WS_INV    655360u   // 131072 f per-token LN rsqrt
#define WS_MASK8  1179648u  // 131072 bytes expanded mask
#define WS_SCORES 2097152u  // 16 MiB scores[b][h][t][n]

// ---------- mask dtype detection (bool may arrive as i32 / u8 / f32) ----------
__global__ void tap_detect(const unsigned* mraw, int* flag){
  int tid = threadIdx.x;
  if (tid == 0) *flag = 0;
  __syncthreads();
  int f = 0;
  for (int i = tid; i < NTOK/4; i += 256){   // read only first NTOK bytes (safe for all layouts)
    unsigned v = mraw[i];
    if (v == 0x3f800000u) f |= 2;            // float32 1.0 pattern -> float layout
    else if (v & ~1u)     f |= 1;            // packed bytes
  }
  if (f) atomicOr(flag, f);
}

__global__ void tap_mask(const void* mraw, const int* flag, unsigned char* m8){
  int i = blockIdx.x*256 + threadIdx.x;
  int fl = *flag;
  unsigned char m;
  if (fl & 2)      m = (((const float*)mraw)[i] != 0.0f);
  else if (fl & 1) m = (((const unsigned char*)mraw)[i] != 0);
  else             m = (((const int*)mraw)[i] != 0);
  m8[i] = m;
}

// ---------- fold query path: G2[ht][j], C1[ht], C0[ht] ----------
// score[n][ht] = inv_n*(x_n . G2[ht] - mean_n*C1[ht]) + C0[ht]
__global__ void tap_prep(const float* q, const float* ipw, const float* ipb,
                         const float* pre_g, const float* pre_b,
                         const float* q_g, const float* q_b, const float* log_tau,
                         float* G2, float* C1, float* C0){
  __shared__ float query[Tt][Dd];
  __shared__ float qps[HDd];
  __shared__ float red[256];
  int tid = threadIdx.x;
  int ht = blockIdx.x;           // = h*T + t
  int h = ht >> 2, t = ht & 3;
  float tau = expf(log_tau[0]);
  tau = fminf(fmaxf(tau, 0.1f), 10.0f);
  float itau = 1.0f / tau;
  int wv = tid >> 6, lane = tid & 63;
  { // LN of q rows (wave per row), all 4 rows redundantly per block
    const float* qr = q + wv*Dd;
    float s = 0.f, ss = 0.f;
    for (int j = lane; j < Dd; j += 64){ float x = qr[j]; s += x; ss += x*x; }
    #pragma unroll
    for (int off = 32; off; off >>= 1){ s += __shfl_down(s, off); ss += __shfl_down(ss, off); }
    s = __shfl(s, 0); ss = __shfl(ss, 0);
    float mean = s * (1.f/Dd);
    float var  = ss * (1.f/Dd) - mean*mean;
    float inv  = rsqrtf(var + 1e-5f);
    for (int j = lane; j < Dd; j += 64){
      float x = qr[j];
      query[wv][j] = ((x - mean)*inv*q_g[j] + q_b[j]) * itau;
    }
  }
  __syncthreads();
  { // qp[d] = query[t] . wq[h*64+d] + bq   (4 threads per output)
    int d = tid >> 2, sub = tid & 3;
    int i = h*HDd + d;
    const float* wrow = ipw + (size_t)i*Dd;
    float acc = 0.f;
    int j0 = sub*128;
    for (int j = 0; j < 128; ++j) acc += query[t][j0+j]*wrow[j0+j];
    red[tid] = acc;
    __syncthreads();
    if (sub == 0) qps[d] = red[tid]+red[tid+1]+red[tid+2]+red[tid+3] + ipb[i];
    __syncthreads();
  }
  float c1p = 0.f, c0p = 0.f;
  for (int jj = 0; jj < 2; ++jj){
    int j = tid + jj*256;
    float acc = 0.f;
    #pragma unroll 8
    for (int d = 0; d < HDd; ++d)
      acc += qps[d] * ipw[(size_t)(Dd + h*HDd + d)*Dd + j];
    float w2 = acc * 0.125f;          // 1/sqrt(HD)
    float g2 = w2 * pre_g[j];
    G2[ht*Dd + j] = g2;
    c1p += g2;
    c0p += w2 * pre_b[j];
  }
  if (tid < HDd) c0p += qps[tid] * ipb[Dd + h*HDd + tid] * 0.125f;  // bk term
  red[tid] = c1p; __syncthreads();
  for (int s = 128; s; s >>= 1){ if (tid < s) red[tid] += red[tid+s]; __syncthreads(); }
  if (tid == 0) C1[ht] = red[0];
  __syncthreads();
  red[tid] = c0p; __syncthreads();
  for (int s = 128; s; s >>= 1){ if (tid < s) red[tid] += red[tid+s]; __syncthreads(); }
  if (tid == 0) C0[ht] = red[0];
}

// ---------- main: fused LN-stats + register-tiled 32-way GEMV ----------
// Block: 64 tokens x 32 ht. Thread (tg=tid&15, hp=tid>>4) owns tokens
// {tg, tg+16, tg+32, tg+48} and ht {hp, hp+16} -> 8 accumulators,
// 32 FMA per 6 LDS b128 reads. K processed in 4 chunks of 128; G2 chunk
// staged in LDS. LN stats accumulated during staging (fixed row ownership,
// deterministic order), reduced with width-32 shuffles.
__global__ __launch_bounds__(256, 3) void tap_scores(
    const float* __restrict__ tokens, const float* __restrict__ G2,
    const float* __restrict__ C1, const float* __restrict__ C0,
    float* __restrict__ scores, float* __restrict__ meanw, float* __restrict__ invw){
  __shared__ float4 xt4[64*33];      // 64 rows, stride 33 f4 (pad: bank start 4*(tg) -> 8 quads x2)
  __shared__ float4 g2s4[32*33];     // 32 ht rows, stride 33 f4
  __shared__ float smean[64], sinv[64];
  int tid = threadIdx.x;
  int tg = tid & 15, hp = tid >> 4;
  int ht0 = hp, ht1 = hp + 16;
  size_t t0 = (size_t)blockIdx.x * 64;
  const float4* tokv = (const float4*)tokens;   // row stride 128 f4
  const float4* G2v  = (const float4*)G2;       // row stride 128 f4
  int colL = tid & 31, rowBase = tid >> 5;      // staging coords
  float acc[4][2] = {{0.f,0.f},{0.f,0.f},{0.f,0.f},{0.f,0.f}};
  float ps[8] = {0,0,0,0,0,0,0,0}, pss[8] = {0,0,0,0,0,0,0,0};
  for (int c = 0; c < 4; ++c){
    // stage token chunk (coalesced), accumulate LN partials
    #pragma unroll
    for (int i = 0; i < 8; ++i){
      int row = rowBase + 8*i;
      float4 v = tokv[(t0 + row)*128 + c*32 + colL];
      xt4[row*33 + colL] = v;
      ps[i]  += v.x + v.y + v.z + v.w;
      pss[i] += v.x*v.x + v.y*v.y + v.z*v.z + v.w*v.w;
    }
    // stage G2 chunk
    #pragma unroll
    for (int i = 0; i < 4; ++i){
      int p = tid + 256*i;
      int row = p >> 5;                 // 0..31
      g2s4[row*33 + colL] = G2v[row*128 + c*32 + colL];
    }
    __syncthreads();
    const float4* xb = xt4 + tg*33;
    #pragma unroll 8
    for (int j4 = 0; j4 < 32; ++j4){
      float4 g0 = g2s4[ht0*33 + j4];
      float4 g1 = g2s4[ht1*33 + j4];
      #pragma unroll
      for (int r = 0; r < 4; ++r){
        float4 x = xb[r*528 + j4];      // row tg+16r
        acc[r][0] += x.x*g0.x + x.y*g0.y + x.z*g0.z + x.w*g0.w;
        acc[r][1] += x.x*g1.x + x.y*g1.y + x.z*g1.z + x.w*g1.w;
      }
    }
    __syncthreads();
  }
  // LN stats reduce: rows rowBase+8i owned by the 32 threads sharing tid>>5
  #pragma unroll
  for (int i = 0; i < 8; ++i){
    float s = ps[i], ss = pss[i];
    #pragma unroll
    for (int off = 16; off; off >>= 1){
      s  += __shfl_down(s,  off, 32);
      ss += __shfl_down(ss, off, 32);
    }
    if ((tid & 31) == 0){
      int row = rowBase + 8*i;
      float mean = s * (1.f/512.f);
      float var  = ss * (1.f/512.f) - mean*mean;
      float inv  = rsqrtf(var + 1e-5f);
      smean[row] = mean; sinv[row] = inv;
      meanw[t0 + row] = mean; invw[t0 + row] = inv;
    }
  }
  __syncthreads();
  float c10 = C1[ht0], c11 = C1[ht1], c00 = C0[ht0], c01 = C0[ht1];
  int b  = (int)(t0 >> 13);
  int n0 = (int)(t0 & 8191);
  float* s0p = scores + ((size_t)(b*HTc + ht0))*Nn + n0 + tg;
  float* s1p = scores + ((size_t)(b*HTc + ht1))*Nn + n0 + tg;
  #pragma unroll
  for (int r = 0; r < 4; ++r){
    int row = tg + 16*r;
    float mean = smean[row], inv = sinv[row];
    s0p[16*r] = inv*(acc[r][0] - mean*c10) + c00;
    s1p[16*r] = inv*(acc[r][1] - mean*c11) + c01;
  }
}

// ---------- per-(b,h,t) masked softmax normalizers ----------
__global__ void tap_norm(const float* __restrict__ scores, const unsigned char* __restrict__ m8,
                         float* __restrict__ mrow, float* __restrict__ lrow){
  int R = blockIdx.x;                  // b*32 + ht
  int b = R >> 5;
  const float* srow = scores + (size_t)R*Nn;
  const unsigned char* mk = m8 + b*Nn;
  int tid = threadIdx.x;
  int wv = tid >> 6, lane = tid & 63;
  __shared__ float r4[4];
  float v[32];
  float mx = -1e30f;
  #pragma unroll
  for (int i = 0; i < 32; ++i){
    int n = tid + i*256;
    float s = srow[n];
    v[i] = mk[n] ? -1e30f : s;
    mx = fmaxf(mx, v[i]);
  }
  #pragma unroll
  for (int off = 32; off; off >>= 1) mx = fmaxf(mx, __shfl_down(mx, off));
  if (lane == 0) r4[wv] = mx;
  __syncthreads();
  mx = fmaxf(fmaxf(r4[0], r4[1]), fmaxf(r4[2], r4[3]));
  float se = 0.f;
  #pragma unroll
  for (int i = 0; i < 32; ++i) se += expf(v[i] - mx);
  #pragma unroll
  for (int off = 32; off; off >>= 1) se += __shfl_down(se, off);
  __syncthreads();
  if (lane == 0) r4[wv] = se;
  __syncthreads();
  if (tid == 0){ mrow[R] = mx; lrow[R] = r4[0]+r4[1]+r4[2]+r4[3]; }
}

// ---------- per-(b,t): alpha, prune via compaction, fallback, exact top-64 set ----------
// Key facts used: (1) after the first normalization sum(alpha)<=1, so at most
// 1000 entries can be >= PRUNE=1e-3 -> compact survivor list <= 1024.
// (2) w = topv / sum(topv) in the pool, so any positive rescaling of the stored
// values cancels -> store raw pruned values, skip the f2 renormalization.
// (3) zero-valued top-k slots get w=0 and contribute nothing -> only the
// nonzero selected SET must match jax (ties broken by smaller index).
__global__ void tap_alpha(const float* __restrict__ scores, const unsigned char* __restrict__ m8,
                          const float* __restrict__ mrow, const float* __restrict__ lrow,
                          float* __restrict__ topw, int* __restrict__ topi){
  __shared__ float av[Nn];            // 32 KB
  __shared__ float lv[1024];
  __shared__ int   li[1024];
  __shared__ float rv[4]; __shared__ int ri[4]; __shared__ int rp[4];
  __shared__ int cnt; __shared__ int sArg;
  int bt = blockIdx.x;
  int b = bt >> 2, t = bt & 3;
  int tid = threadIdx.x;
  int wv = tid >> 6, lane = tid & 63;
  const unsigned char* mk = m8 + b*Nn;
  if (tid == 0) cnt = 0;
  float mh[Hh], il[Hh];
  const float* srows[Hh];
  #pragma unroll
  for (int h = 0; h < Hh; ++h){
    int R = b*HTc + h*Tt + t;
    mh[h] = mrow[R];
    il[h] = 1.0f / lrow[R];
    srows[h] = scores + (size_t)R*Nn;
  }
  float lsum = 0.f;
  float bvv = -2.f; int bii = 1<<30;
  for (int i = 0; i < 32; ++i){
    int n = tid + i*256;
    float a = 0.f;
    if (!mk[n]){
      #pragma unroll
      for (int h = 0; h < Hh; ++h) a += expf(srows[h][n] - mh[h]) * il[h];
      a *= 0.125f;   // mean over heads
    }
    av[n] = a;
    lsum += a;
    float bb = mk[n] ? -1.f : a;
    if (bb > bvv || (bb == bvv && n < bii)){ bvv = bb; bii = n; }
  }
  #pragma unroll
  for (int off = 32; off; off >>= 1) lsum += __shfl_down(lsum, off);
  if (lane == 0) rv[wv] = lsum;
  __syncthreads();
  float Sall = rv[0]+rv[1]+rv[2]+rv[3];
  // argmax for fallback (value desc, index asc)
  #pragma unroll
  for (int off = 32; off; off >>= 1){
    float ov = __shfl_down(bvv, off);
    int   oi = __shfl_down(bii, off);
    if (ov > bvv || (ov == bvv && oi < bii)){ bvv = ov; bii = oi; }
  }
  __syncthreads();
  if (lane == 0){ rv[wv] = bvv; ri[wv] = bii; }
  __syncthreads();
  if (tid == 0){
    float bv2 = rv[0]; int bi2 = ri[0];
    for (int w2 = 1; w2 < 4; ++w2)
      if (rv[w2] > bv2 || (rv[w2] == bv2 && ri[w2] < bi2)){ bv2 = rv[w2]; bi2 = ri[w2]; }
    sArg = bi2;
  }
  __syncthreads();
  float f1 = 1.0f / fmaxf(Sall, EPSc);
  // compact survivors (normalized value >= PRUNE)
  for (int i = 0; i < 32; ++i){
    int n = tid + i*256;
    float x = av[n] * f1;
    if (x >= PRUNEc){
      int id = atomicAdd(&cnt, 1);
      if (id < 1024){ lv[id] = x; li[id] = n; }
    }
  }
  __syncthreads();
  int L = cnt;
  float* tw = topw + bt*KS;
  int*   ti = topi + bt*KS;
  if (L == 0){                         // fallback: onehot at argmax
    if (tid < KS){ tw[tid] = (tid == 0) ? 1.f : 0.f; ti[tid] = (tid == 0) ? sArg : 0; }
    return;
  }
  if (L <= KS){                        // all survivors selected; zero-fill rest
    if (tid < KS){ tw[tid] = (tid < L) ? lv[tid] : 0.f; ti[tid] = (tid < L) ? li[tid] : 0; }
    return;
  }
  // top-64 extraction over short list (L <= 1000)
  for (int k = 0; k < KS; ++k){
    float bv = -1.f; int bn = 1<<30; int bp = -1;
    for (int j = tid; j < L; j += 256){
      float x = lv[j]; int nn = li[j];
      if (x > bv || (x == bv && nn < bn)){ bv = x; bn = nn; bp = j; }
    }
    #pragma unroll
    for (int off = 32; off; off >>= 1){
      float ov = __shfl_down(bv, off);
      int   on = __shfl_down(bn, off);
      int   op = __shfl_down(bp, off);
      if (ov > bv || (ov == bv && on < bn)){ bv = ov; bn = on; bp = op; }
    }
    if (lane == 0){ rv[wv] = bv; ri[wv] = bn; rp[wv] = bp; }
    __syncthreads();
    if (tid == 0){
      float bb = rv[0]; int bj = ri[0]; int pp = rp[0];
      for (int w2 = 1; w2 < 4; ++w2)
        if (rv[w2] > bb || (rv[w2] == bb && ri[w2] < bj)){ bb = rv[w2]; bj = ri[w2]; pp = rp[w2]; }
      tw[k] = bb; ti[k] = bj;
      lv[pp] = -1.f;                   // consume
    }
    __syncthreads();
  }
}

// ---------- pooling: u = sum_k w_k*normed_k (LN folded via saved stats), then u@wv^T ----------
__global__ void tap_pool(const float* __restrict__ tokens, const float* __restrict__ ipw,
                         const float* __restrict__ ipb,
                         const float* __restrict__ pre_g, const float* __restrict__ pre_b,
                         const float* __restrict__ meanw, const float* __restrict__ invw,
                         const float* __restrict__ topw, const int* __restrict__ topi,
                         float* __restrict__ out){
  __shared__ float wk_[KS]; __shared__ int rk_[KS];
  __shared__ float coeff[KS];
  __shared__ __align__(16) float u[Dd];
  __shared__ float sW, sS;
  int bt = blockIdx.x;
  int b = bt >> 2;
  int tid = threadIdx.x;
  if (tid < KS){ wk_[tid] = topw[bt*KS + tid]; rk_[tid] = topi[bt*KS + tid]; }
  __syncthreads();
  if (tid < KS){
    float v = wk_[tid];
    #pragma unroll
    for (int off = 32; off; off >>= 1) v += __shfl_down(v, off);
    if (tid == 0) sW = v;
  }
  __syncthreads();
  float sumw = sW;
  float Winv = 1.0f / fmaxf(sumw, EPSc);
  float Wn   = sumw * Winv;
  if (tid < KS){
    int n = rk_[tid];
    float mk = meanw[(size_t)b*Nn + n];
    float ik = invw [(size_t)b*Nn + n];
    float wn = wk_[tid] * Winv;
    coeff[tid] = wn * ik;
    float sp = wn * mk * ik;
    #pragma unroll
    for (int off = 32; off; off >>= 1) sp += __shfl_down(sp, off);
    if (tid == 0) sS = sp;
  }
  __syncthreads();
  float Sv = sS;
  int d0 = tid, d1 = tid + 256;
  float acc0 = 0.f, acc1 = 0.f;
  #pragma unroll 4
  for (int k = 0; k < KS; ++k){        // branchless: c==0 rows contribute 0
    float c = coeff[k];
    const float* xr = tokens + ((size_t)b*Nn + rk_[k])*Dd;
    acc0 = fmaf(c, xr[d0], acc0);
    acc1 = fmaf(c, xr[d1], acc1);
  }
  u[d0] = pre_g[d0]*(acc0 - Sv) + pre_b[d0]*Wn;
  u[d1] = pre_g[d1]*(acc1 - Sv) + pre_b[d1]*Wn;
  __syncthreads();
  const float4* u4 = (const float4*)u;
  const float4* w0 = (const float4*)(ipw + (size_t)(2*Dd + d0)*Dd);
  const float4* w1 = (const float4*)(ipw + (size_t)(2*Dd + d1)*Dd);
  float o0 = 0.f, o1 = 0.f;
  #pragma unroll 4
  for (int j4 = 0; j4 < 128; ++j4){
    float4 uu = u4[j4];
    float4 a = w0[j4], c = w1[j4];
    o0 += uu.x*a.x + uu.y*a.y + uu.z*a.z + uu.w*a.w;
    o1 += uu.x*c.x + uu.y*c.y + uu.z*c.z + uu.w*c.w;
  }
  out[bt*Dd + d0] = o0 + Wn*ipb[2*Dd + d0];
  out[bt*Dd + d1] = o1 + Wn*ipb[2*Dd + d1];
}

extern "C" void kernel_launch(void* const* d_in, const int* in_sizes, int n_in,
                              void* d_out, int out_size, void* d_ws, size_t ws_size,
                              hipStream_t stream){
  const float* tokens = (const float*)d_in[0];
  const void*  kpm    = d_in[1];
  const float* q      = (const float*)d_in[2];
  const float* ipw    = (const float*)d_in[3];
  const float* ipb    = (const float*)d_in[4];
  const float* pre_g  = (const float*)d_in[5];
  const float* pre_b  = (const float*)d_in[6];
  const float* q_g    = (const float*)d_in[7];
  const float* q_b    = (const float*)d_in[8];
  const float* ltau   = (const float*)d_in[9];
  char* ws = (char*)d_ws;
  float* G2    = (float*)(ws + WS_G2);
  float* C1    = (float*)(ws + WS_C1);
  float* C0    = (float*)(ws + WS_C0);
  float* mrow  = (float*)(ws + WS_M);
  float* lrow  = (float*)(ws + WS_L);
  float* topwv = (float*)(ws + WS_TOPW);
  int*   topiv = (int*)  (ws + WS_TOPI);
  int*   flag  = (int*)  (ws + WS_FLAG);
  float* meanw = (float*)(ws + WS_MEAN);
  float* invw  = (float*)(ws + WS_INV);
  unsigned char* m8 = (unsigned char*)(ws + WS_MASK8);
  float* scores = (float*)(ws + WS_SCORES);
  float* out = (float*)d_out;

  hipLaunchKernelGGL(tap_detect, dim3(1), dim3(256), 0, stream, (const unsigned*)kpm, flag);
  hipLaunchKernelGGL(tap_mask,   dim3(NTOK/256), dim3(256), 0, stream, kpm, flag, m8);
  hipLaunchKernelGGL(tap_prep,   dim3(HTc), dim3(256), 0, stream,
                     q, ipw, ipb, pre_g, pre_b, q_g, q_b, ltau, G2, C1, C0);
  hipLaunchKernelGGL(tap_scores, dim3(NTOK/64), dim3(256), 0, stream,
                     tokens, G2, C1, C0, scores, meanw, invw);
  hipLaunchKernelGGL(tap_norm,   dim3(Bb*HTc), dim3(256), 0, stream, scores, m8, mrow, lrow);
  hipLaunchKernelGGL(tap_alpha,  dim3(Bb*Tt), dim3(256), 0, stream,
                     scores, m8, mrow, lrow, topwv, topiv);
  hipLaunchKernelGGL(tap_pool,   dim3(Bb*Tt), dim3(256), 0, stream,
                     tokens, ipw, ipb, pre_g, pre_b, meanw, invw, topwv, topiv, out);
}